// Round 13
// baseline (6262.827 us; speedup 1.0000x reference)
//
#include <hip/hip_runtime.h>
#include <stdint.h>

// LSTM: T=512, B=64, E=1024, H=1024. out[t] = h_{t+1} (fp32).
// Phase A: xw = x @ w_x + bias (bf16 MFMA GEMM, parallel over all T).
// Phase B: persistent kernel, 64 WGs x 256 thr (4 waves). Wave w: batch rows
//          [w*16,+16) x all 64 gate cols; W from LDS (fragment-major,
//          conflict-free). 4 independent per-wave chains, zero syncthreads in
//          the step loop. r12 transport + NEW: byte-packed flags — chain w's
//          64 producer flags = bytes [w*64, +64) = ONE 64B L3 line; a wave's
//          poll reads 1 line/iteration (16x less poll traffic than r12).
//          Wrap-safe compare ((v-t)&0xFF)<2 (chain skew is provably <=1 step).
//          K-chunk rotation (rot=wg&3), two-phase poll, cacheable A loads,
//          nt xw prefetch 2 steps ahead, counted vmcnt (8/0/24/16).
// Phase C: k3_out converts hbuf[1..512] -> fp32 outp (nt stores).

#define TSTEPS 512
#define NBATCH 64
#define NHID   1024
#define NWG2   64
#define AGENT  __HIP_MEMORY_SCOPE_AGENT

typedef __attribute__((ext_vector_type(8))) short bf16x8;
typedef __attribute__((ext_vector_type(4))) float f32x4;
typedef __attribute__((ext_vector_type(4))) int   i32x4;
typedef __attribute__((ext_vector_type(4))) float fl4;

__device__ __forceinline__ uint16_t f2bf(float f){
  uint32_t u = __float_as_uint(f);
  u += 0x7fffu + ((u >> 16) & 1u);       // round-to-nearest-even
  return (uint16_t)(u >> 16);
}
__device__ __forceinline__ float bf2f(uint16_t b){
  return __uint_as_float(((uint32_t)b) << 16);
}
__device__ __forceinline__ float sigm(float x){ return 1.0f/(1.0f + __expf(-x)); }
__device__ __forceinline__ float tanhfast(float x){ return 1.0f - 2.0f/(__expf(2.0f*x) + 1.0f); }
__device__ __forceinline__ bf16x8 as_bf(i32x4 v){
  union { i32x4 i; bf16x8 b; } u; u.i = v; return u.b;
}

// ---------------- K0a: fp32 -> bf16 convert (embeds) ----------------
__global__ void k0a_cvt(const float* __restrict__ in, uint16_t* __restrict__ outp, int n8){
  int stride = gridDim.x * blockDim.x;
  for (int i = blockIdx.x * blockDim.x + threadIdx.x; i < n8; i += stride){
    const fl4* p = (const fl4*)(in + (size_t)i * 8);
    fl4 v0 = p[0], v1 = p[1];
    union { uint16_t u[8]; i32x4 v; } r;
    r.u[0]=f2bf(v0.x); r.u[1]=f2bf(v0.y); r.u[2]=f2bf(v0.z); r.u[3]=f2bf(v0.w);
    r.u[4]=f2bf(v1.x); r.u[5]=f2bf(v1.y); r.u[6]=f2bf(v1.z); r.u[7]=f2bf(v1.w);
    *(i32x4*)(outp + (size_t)i * 8) = r.v;
  }
}

// ---------------- K0b: w [2048][4096] f32 -> wT [4096][2048] bf16 ----------------
__global__ void k0b_trans(const float* __restrict__ w, uint16_t* __restrict__ wT){
  __shared__ float tile[64 * 65];
  int k0 = blockIdx.x * 64;
  int n0 = blockIdx.y * 64;
  int tid = threadIdx.x;
  int r  = tid >> 2;
  int cq = (tid & 3) * 16;
#pragma unroll
  for (int i = 0; i < 4; ++i){
    fl4 v = *(const fl4*)(w + (size_t)(k0 + r) * 4096 + n0 + cq + i * 4);
    tile[r*65 + cq + i*4 + 0] = v.x;
    tile[r*65 + cq + i*4 + 1] = v.y;
    tile[r*65 + cq + i*4 + 2] = v.z;
    tile[r*65 + cq + i*4 + 3] = v.w;
  }
  __syncthreads();
  union { uint16_t u[8]; i32x4 v; } a, b;
#pragma unroll
  for (int i = 0; i < 8; ++i) a.u[i] = f2bf(tile[(cq + i) * 65 + r]);
#pragma unroll
  for (int i = 0; i < 8; ++i) b.u[i] = f2bf(tile[(cq + 8 + i) * 65 + r]);
  *(i32x4*)(wT + (size_t)(n0 + r) * 2048 + k0 + cq)     = a.v;
  *(i32x4*)(wT + (size_t)(n0 + r) * 2048 + k0 + cq + 8) = b.v;
}

// ---------------- K1: xw = ebf[32768,1024] @ w_x + bias -> bf16 (nt stores) ----------------
__launch_bounds__(256, 2)
__global__ void k1_xw(const uint16_t* __restrict__ ebf, const uint16_t* __restrict__ wT,
                      const float* __restrict__ bias, uint16_t* __restrict__ xw){
  __shared__ char sm[32768];
  char* As = sm;
  char* Bs = sm + 16384;
  int bid = blockIdx.x;
  int nt = bid & 31, mt = bid >> 5;
  int m0 = mt * 128, n0 = nt * 128;
  int tid = threadIdx.x;
  int lane = tid & 63, wid = tid >> 6;
  int wr = wid >> 1, wc = wid & 1;

  f32x4 zero = {0.f, 0.f, 0.f, 0.f};
  f32x4 acc[4][4];
#pragma unroll
  for (int mi = 0; mi < 4; ++mi)
#pragma unroll
    for (int ni = 0; ni < 4; ++ni) acc[mi][ni] = zero;

  for (int kt = 0; kt < 16; ++kt){
    __syncthreads();
#pragma unroll
    for (int i = 0; i < 4; ++i){
      int L = i * 256 + tid;
      int row = L >> 3, c = L & 7;
      i32x4 va = *(const i32x4*)(ebf + (size_t)(m0 + row) * 1024 + kt * 64 + c * 8);
      *(i32x4*)(As + row * 128 + ((c ^ (row & 7)) * 16)) = va;
      i32x4 vb = *(const i32x4*)(wT + (size_t)(n0 + row) * 2048 + 1024 + kt * 64 + c * 8);
      *(i32x4*)(Bs + row * 128 + ((c ^ (row & 7)) * 16)) = vb;
    }
    __syncthreads();
#pragma unroll
    for (int kk = 0; kk < 2; ++kk){
      bf16x8 a[4], b[4];
      int ci = kk * 4 + (lane >> 4);
#pragma unroll
      for (int mi = 0; mi < 4; ++mi){
        int rl = wr * 64 + mi * 16 + (lane & 15);
        a[mi] = *(const bf16x8*)(As + rl * 128 + ((ci ^ (rl & 7)) * 16));
      }
#pragma unroll
      for (int ni = 0; ni < 4; ++ni){
        int sl = wc * 64 + ni * 16 + (lane & 15);
        b[ni] = *(const bf16x8*)(Bs + sl * 128 + ((ci ^ (sl & 7)) * 16));
      }
#pragma unroll
      for (int mi = 0; mi < 4; ++mi)
#pragma unroll
        for (int ni = 0; ni < 4; ++ni)
          acc[mi][ni] = __builtin_amdgcn_mfma_f32_16x16x32_bf16(a[mi], b[ni], acc[mi][ni], 0, 0, 0);
    }
  }
  float bcol[4];
#pragma unroll
  for (int ni = 0; ni < 4; ++ni) bcol[ni] = bias[n0 + wc * 64 + ni * 16 + (lane & 15)];
#pragma unroll
  for (int mi = 0; mi < 4; ++mi)
#pragma unroll
    for (int ni = 0; ni < 4; ++ni)
#pragma unroll
      for (int jj = 0; jj < 4; ++jj){
        int rg = m0 + wr * 64 + mi * 16 + (lane >> 4) * 4 + jj;
        int cg = n0 + wc * 64 + ni * 16 + (lane & 15);
        __builtin_nontemporal_store(f2bf(acc[mi][ni][jj] + bcol[ni]),
                                    &xw[(size_t)rg * 4096 + cg]);
      }
}

// ---------------- K2: persistent recurrent kernel ----------------
// WP (131072B): fragment-major: fragment (kc,g,lane) at ((kc*4+g)*64+lane)*16,
// holding w_h[k=kc*32+q*8..+8][col=g*1024+j0+rr].
// K split into 4 chunks of 8 kc; chunk c depends on producer WGs... (rows via
// chains) producers [c*16, c*16+16). WG processes chunks in order (rot+b)&3.
// Flags (BYTE-packed): flagsB[w*64 + wg]; chain w = bytes [w*64,+64) = 1 line.
#define LDA(k, BASE, OFF) asm volatile("global_load_dwordx4 %0, %1, off offset:" #OFF \
                                 : "=v"(ap[k]) : "v"(BASE) : "memory")   // cacheable
#define LDCHUNK(B, BASE) \
  LDA((B)*8+0, BASE, 0);   LDA((B)*8+1, BASE, 64);  LDA((B)*8+2, BASE, 128); LDA((B)*8+3, BASE, 192); \
  LDA((B)*8+4, BASE, 256); LDA((B)*8+5, BASE, 320); LDA((B)*8+6, BASE, 384); LDA((B)*8+7, BASE, 448)
#define WAITV(N) do { asm volatile("s_waitcnt vmcnt(" #N ")" ::: "memory"); \
                      __builtin_amdgcn_sched_barrier(0); } while(0)
#define GBLKR(B, WPC) \
  _Pragma("unroll") \
  for (int i = 0; i < 8; ++i){ \
    bf16x8 a = as_bf(ap[(B) * 8 + i]); \
    _Pragma("unroll") \
    for (int g = 0; g < 4; ++g){ \
      bf16x8 b = *(const bf16x8*)((WPC) + ((i * 4 + g) << 10) + (lane << 4)); \
      acc[g] = __builtin_amdgcn_mfma_f32_16x16x32_bf16(a, b, acc[g], 0, 0, 0); \
    } \
  }
#define POLLB(V, P) asm volatile("global_load_ubyte %0, %1, off sc0 sc1\n\ts_waitcnt vmcnt(0)" \
                                  : "=v"(V) : "v"(P) : "memory")

__launch_bounds__(256, 1)
__global__ void k2_rec(const uint16_t* __restrict__ xw, const uint16_t* __restrict__ wT,
                       uint16_t* __restrict__ hbuf, uint8_t* __restrict__ flagsB,
                       float* __restrict__ outp){
  extern __shared__ char sm[];
  char* WP = sm;                       // 131072

  int tid  = threadIdx.x;
  int lane = tid & 63;
  int w    = tid >> 6;                 // wave id = row block = chain id
  int wg = blockIdx.x;
  int j0 = wg * 16;
  int rot = wg & 3;                    // chunk rotation class

  // pin w_h slice in fragment-major layout
#pragma unroll
  for (int i = 0; i < 32; ++i){
    int L = i * 256 + tid;             // fragment id 0..8191
    int kc = L >> 8;
    int g  = (L >> 6) & 3;
    int l6 = L & 63;
    int q_ = (l6 >> 4) & 3;
    int rr_ = l6 & 15;
    i32x4 v = *(const i32x4*)(wT + (size_t)(g * 1024 + j0 + rr_) * 2048 + kc * 32 + q_ * 8);
    *(i32x4*)(WP + (size_t)L * 16) = v;
  }
  __syncthreads();                     // only barrier in the kernel

  const int r0 = w * 16;
  const int q  = lane >> 4;
  const int rr = lane & 15;

  // poll assignment: lane group g checks producer WG ((rot+g)&3)*16 + (lane&15)
  const int chk = (rot + (lane >> 4)) & 3;
  const uint8_t* fpoll = flagsB + (w << 6) + (chk << 4) + (lane & 15);
  uint8_t* fpost = flagsB + (w << 6) + wg;

  // chunk bases (WP side; A side is per-step)
  char* WPc0 = WP + (((rot + 0) & 3) << 15);
  char* WPc1 = WP + (((rot + 1) & 3) << 15);
  char* WPc2 = WP + (((rot + 2) & 3) << 15);
  char* WPc3 = WP + (((rot + 3) & 3) << 15);
  const int aOff0 = ((rot + 0) & 3) << 8;   // elements: chunk * 8kc * 32
  const int aOff1 = ((rot + 1) & 3) << 8;
  const int aOff2 = ((rot + 2) & 3) << 8;
  const int aOff3 = ((rot + 3) & 3) << 8;

  float creg[4] = {0.f, 0.f, 0.f, 0.f};

  // xw 3-buffer rotation
  uint16_t xc[4][4], xn[4][4];
  {
    const uint16_t* xp0 = xw + j0 + rr;
    const uint16_t* xp1 = xw + (size_t)1 * (64 * 4096) + j0 + rr;
#pragma unroll
    for (int g = 0; g < 4; ++g)
#pragma unroll
      for (int p = 0; p < 4; ++p){
        xc[g][p] = xp0[(size_t)(r0 + q * 4 + p) * 4096 + g * 1024];
        xn[g][p] = xp1[(size_t)(r0 + q * 4 + p) * 4096 + g * 1024];
      }
  }

  for (int t = 0; t < TSTEPS; ++t){
    // ---- phase-1 poll: chunks {rot, rot+1} (lower 32 lanes' producers) ----
    // flag byte semantics: ((v - t) & 0xFF) < 2  <=>  completed-steps in {t, t+1}
    bool need2 = false;
    int t8 = t & 0xFF;
    if (t > 0){
      while (true){
        int v; POLLB(v, fpoll);
        unsigned long long m = __ballot(((v - t8) & 0xFF) < 2);
        if ((m & 0xFFFFFFFFull) == 0xFFFFFFFFull){
          need2 = ((m >> 32) != 0xFFFFFFFFull);
          break;
        }
        __builtin_amdgcn_s_sleep(1);
      }
    }

    const uint16_t* hsrc = hbuf + (size_t)t * (NBATCH * NHID);
    const uint16_t* aB = hsrc + (size_t)(r0 + rr) * 1024 + q * 8;

    // ---- A chunks rot, rot+1 (16 loads) ----
    i32x4 ap[32];
    LDCHUNK(0, aB + aOff0);
    LDCHUNK(1, aB + aOff1);

    f32x4 acc[4];
#pragma unroll
    for (int g = 0; g < 4; ++g) acc[g] = (f32x4){0.f, 0.f, 0.f, 0.f};

    WAITV(8);  GBLKR(0, WPc0);
    WAITV(0);  GBLKR(1, WPc1);

    // ---- phase-2 poll: confirm remaining 32 producers (usually instant) ----
    if (need2){
      while (true){
        int v; POLLB(v, fpoll);
        unsigned long long m = __ballot(((v - t8) & 0xFF) < 2);
        if ((m >> 32) == 0xFFFFFFFFull) break;
        __builtin_amdgcn_s_sleep(1);
      }
    }

    // ---- A chunks rot+2, rot+3 (16) + xw t+2 nt prefetch (16) ----
    LDCHUNK(2, aB + aOff2);
    LDCHUNK(3, aB + aOff3);
    uint16_t xn2[4][4];
    {
      int tn = (t < TSTEPS - 2) ? t + 2 : TSTEPS - 1;   // uniform load count
      const uint16_t* xp = xw + (size_t)tn * (64 * 4096) + j0 + rr;
#pragma unroll
      for (int g = 0; g < 4; ++g)
#pragma unroll
        for (int p = 0; p < 4; ++p)
          xn2[g][p] = __builtin_nontemporal_load(
                        &xp[(size_t)(r0 + q * 4 + p) * 4096 + g * 1024]);
    }

    WAITV(24); GBLKR(2, WPc2);
    WAITV(16); GBLKR(3, WPc3);

    // ---- epilogue: in-register gate math; ONLY 4 bf16 sc1 stores ----
    uint16_t* hdst = hbuf + (size_t)(t + 1) * (NBATCH * NHID);
#pragma unroll
    for (int p = 0; p < 4; ++p){
      float G = acc[0][p] + bf2f(xc[0][p]);
      float I = acc[1][p] + bf2f(xc[1][p]);
      float F = acc[2][p] + bf2f(xc[2][p]);
      float O = acc[3][p] + bf2f(xc[3][p]);
      G = tanhfast(G); I = sigm(I); F = sigm(F); O = sigm(O);
      float c = G * I + creg[p] * F;
      creg[p] = c;
      float h = tanhfast(c) * O;
      __hip_atomic_store(hdst + (size_t)(r0 + q * 4 + p) * 1024 + j0 + rr,
                         f2bf(h), __ATOMIC_RELAXED, AGENT);   // sc1 -> through to L3
    }

    // per-wave drain (4 h-stores + xw loads), then byte flag post (sc0 sc1)
    asm volatile("s_waitcnt vmcnt(0)" ::: "memory");
    if (lane == 0){
      int tv = (t + 1) & 0xFF;
      asm volatile("global_store_byte %0, %1, off sc0 sc1"
                   :: "v"(fpost), "v"(tv) : "memory");
    }

    // rotate xw regs (loads already drained)
#pragma unroll
    for (int g = 0; g < 4; ++g)
#pragma unroll
      for (int p = 0; p < 4; ++p){
        xc[g][p] = xn[g][p];
        xn[g][p] = xn2[g][p];
      }
  }
}

// ---------------- K3: hbuf[1..512] bf16 -> outp fp32 (nt stores) ----------------
__global__ void k3_out(const uint16_t* __restrict__ hb, float* __restrict__ outp, int n8){
  int stride = gridDim.x * blockDim.x;
  for (int i = blockIdx.x * blockDim.x + threadIdx.x; i < n8; i += stride){
    i32x4 v = *(const i32x4*)(hb + (size_t)(NBATCH * NHID) + (size_t)i * 8);
    const uint16_t* u = (const uint16_t*)&v;
    fl4 o0, o1;
    o0.x = bf2f(u[0]); o0.y = bf2f(u[1]); o0.z = bf2f(u[2]); o0.w = bf2f(u[3]);
    o1.x = bf2f(u[4]); o1.y = bf2f(u[5]); o1.z = bf2f(u[6]); o1.w = bf2f(u[7]);
    __builtin_nontemporal_store(o0, (fl4*)(outp + (size_t)i * 8));
    __builtin_nontemporal_store(o1, (fl4*)(outp + (size_t)i * 8 + 4));
  }
}

extern "C" void kernel_launch(void* const* d_in, const int* in_sizes, int n_in,
                              void* d_out, int out_size, void* d_ws, size_t ws_size,
                              hipStream_t stream){
  const float* embeds = (const float*)d_in[0];   // [512,64,1024]
  const float* w      = (const float*)d_in[1];   // [2048,4096]
  const float* bias   = (const float*)d_in[2];   // [4096]
  float* outp = (float*)d_out;
  char* ws = (char*)d_ws;

  const size_t o_ebf = 0;                                   // bf16 [32768][1024]
  const size_t o_wT  = o_ebf + (size_t)32768 * 1024 * 2;    // bf16 [4096][2048]
  const size_t o_xw  = o_wT  + (size_t)4096 * 2048 * 2;     // bf16 [32768][4096]
  const size_t o_hb  = o_xw  + (size_t)32768 * 4096 * 2;    // bf16 [513][64][1024]
  const size_t o_fl  = o_hb  + (size_t)513 * 64 * 1024 * 2; // uint8 [4*64] byte-packed

  uint16_t* ebf  = (uint16_t*)(ws + o_ebf);
  uint16_t* wT   = (uint16_t*)(ws + o_wT);
  uint16_t* xw   = (uint16_t*)(ws + o_xw);
  uint16_t* hbuf = (uint16_t*)(ws + o_hb);
  uint8_t*  flagsB = (uint8_t*)(ws + o_fl);

  hipMemsetAsync(ws + o_hb, 0, (size_t)64 * 1024 * 2, stream);   // h_0 = 0
  hipMemsetAsync(ws + o_fl, 0, 256, stream);                     // flags = 0 every replay

  k0a_cvt<<<2048, 256, 0, stream>>>(embeds, ebf, (512 * 64 * 1024) / 8);
  k0b_trans<<<dim3(32, 64), 256, 0, stream>>>(w, wT);
  k1_xw<<<8192, 256, 0, stream>>>(ebf, wT, bias, xw);

  (void)hipFuncSetAttribute((const void*)k2_rec,
                            hipFuncAttributeMaxDynamicSharedMemorySize, 131072);
  k2_rec<<<NWG2, 256, 131072, stream>>>(xw, wT, hbuf, flagsB, outp);

  k3_out<<<2048, 256, 0, stream>>>(hbuf, outp, (512 * 64 * 1024) / 8);
}

// Round 14
// 3864.161 us; speedup vs baseline: 1.6207x; 1.6207x over previous
//
#include <hip/hip_runtime.h>
#include <stdint.h>

// LSTM: T=512, B=64, E=1024, H=1024. out[t] = h_{t+1} (fp32).
// Phase A: xw = x @ w_x + bias (bf16 MFMA GEMM, parallel over all T).
// Phase B: persistent kernel, 64 WGs x 256 thr (4 waves). Wave w: batch rows
//          [w*16,+16) x all 64 gate cols; W from LDS (fragment-major,
//          conflict-free). 4 independent per-wave chains, zero syncthreads in
//          the step loop. Transport = r12 (proven): packed int flags, 16B
//          stride (4/line, 16 lines/chain — interior optimum: 128B stride is
//          too much poll traffic, 1B packing hotspots 4 L3 lines), sc0 sc1
//          asm poll/post, K-chunk rotation (rot=wg&3). NEW: 4-phase
//          per-chunk readiness — first poll's ballot yields need1/2/3 free;
//          GEMM starts after only 16 producers; later chunks get conditional
//          polls right before their A-loads. Fast-path vmcnt schedule
//          unchanged (8/8/24/16). A cacheable; xw nt-prefetch t+2.
// Phase C: k3_out converts hbuf[1..512] -> fp32 outp (nt stores).

#define TSTEPS 512
#define NBATCH 64
#define NHID   1024
#define NWG2   64
#define FLAGSTRIDE 4         // ints; 16B between flags (r12 optimum)
#define AGENT  __HIP_MEMORY_SCOPE_AGENT

typedef __attribute__((ext_vector_type(8))) short bf16x8;
typedef __attribute__((ext_vector_type(4))) float f32x4;
typedef __attribute__((ext_vector_type(4))) int   i32x4;
typedef __attribute__((ext_vector_type(4))) float fl4;

__device__ __forceinline__ uint16_t f2bf(float f){
  uint32_t u = __float_as_uint(f);
  u += 0x7fffu + ((u >> 16) & 1u);       // round-to-nearest-even
  return (uint16_t)(u >> 16);
}
__device__ __forceinline__ float bf2f(uint16_t b){
  return __uint_as_float(((uint32_t)b) << 16);
}
__device__ __forceinline__ float sigm(float x){ return 1.0f/(1.0f + __expf(-x)); }
__device__ __forceinline__ float tanhfast(float x){ return 1.0f - 2.0f/(__expf(2.0f*x) + 1.0f); }
__device__ __forceinline__ bf16x8 as_bf(i32x4 v){
  union { i32x4 i; bf16x8 b; } u; u.i = v; return u.b;
}

// ---------------- K0a: fp32 -> bf16 convert (embeds) ----------------
__global__ void k0a_cvt(const float* __restrict__ in, uint16_t* __restrict__ outp, int n8){
  int stride = gridDim.x * blockDim.x;
  for (int i = blockIdx.x * blockDim.x + threadIdx.x; i < n8; i += stride){
    const fl4* p = (const fl4*)(in + (size_t)i * 8);
    fl4 v0 = p[0], v1 = p[1];
    union { uint16_t u[8]; i32x4 v; } r;
    r.u[0]=f2bf(v0.x); r.u[1]=f2bf(v0.y); r.u[2]=f2bf(v0.z); r.u[3]=f2bf(v0.w);
    r.u[4]=f2bf(v1.x); r.u[5]=f2bf(v1.y); r.u[6]=f2bf(v1.z); r.u[7]=f2bf(v1.w);
    *(i32x4*)(outp + (size_t)i * 8) = r.v;
  }
}

// ---------------- K0b: w [2048][4096] f32 -> wT [4096][2048] bf16 ----------------
__global__ void k0b_trans(const float* __restrict__ w, uint16_t* __restrict__ wT){
  __shared__ float tile[64 * 65];
  int k0 = blockIdx.x * 64;
  int n0 = blockIdx.y * 64;
  int tid = threadIdx.x;
  int r  = tid >> 2;
  int cq = (tid & 3) * 16;
#pragma unroll
  for (int i = 0; i < 4; ++i){
    fl4 v = *(const fl4*)(w + (size_t)(k0 + r) * 4096 + n0 + cq + i * 4);
    tile[r*65 + cq + i*4 + 0] = v.x;
    tile[r*65 + cq + i*4 + 1] = v.y;
    tile[r*65 + cq + i*4 + 2] = v.z;
    tile[r*65 + cq + i*4 + 3] = v.w;
  }
  __syncthreads();
  union { uint16_t u[8]; i32x4 v; } a, b;
#pragma unroll
  for (int i = 0; i < 8; ++i) a.u[i] = f2bf(tile[(cq + i) * 65 + r]);
#pragma unroll
  for (int i = 0; i < 8; ++i) b.u[i] = f2bf(tile[(cq + 8 + i) * 65 + r]);
  *(i32x4*)(wT + (size_t)(n0 + r) * 2048 + k0 + cq)     = a.v;
  *(i32x4*)(wT + (size_t)(n0 + r) * 2048 + k0 + cq + 8) = b.v;
}

// ---------------- K1: xw = ebf[32768,1024] @ w_x + bias -> bf16 (nt stores) ----------------
__launch_bounds__(256, 2)
__global__ void k1_xw(const uint16_t* __restrict__ ebf, const uint16_t* __restrict__ wT,
                      const float* __restrict__ bias, uint16_t* __restrict__ xw){
  __shared__ char sm[32768];
  char* As = sm;
  char* Bs = sm + 16384;
  int bid = blockIdx.x;
  int nt = bid & 31, mt = bid >> 5;
  int m0 = mt * 128, n0 = nt * 128;
  int tid = threadIdx.x;
  int lane = tid & 63, wid = tid >> 6;
  int wr = wid >> 1, wc = wid & 1;

  f32x4 zero = {0.f, 0.f, 0.f, 0.f};
  f32x4 acc[4][4];
#pragma unroll
  for (int mi = 0; mi < 4; ++mi)
#pragma unroll
    for (int ni = 0; ni < 4; ++ni) acc[mi][ni] = zero;

  for (int kt = 0; kt < 16; ++kt){
    __syncthreads();
#pragma unroll
    for (int i = 0; i < 4; ++i){
      int L = i * 256 + tid;
      int row = L >> 3, c = L & 7;
      i32x4 va = *(const i32x4*)(ebf + (size_t)(m0 + row) * 1024 + kt * 64 + c * 8);
      *(i32x4*)(As + row * 128 + ((c ^ (row & 7)) * 16)) = va;
      i32x4 vb = *(const i32x4*)(wT + (size_t)(n0 + row) * 2048 + 1024 + kt * 64 + c * 8);
      *(i32x4*)(Bs + row * 128 + ((c ^ (row & 7)) * 16)) = vb;
    }
    __syncthreads();
#pragma unroll
    for (int kk = 0; kk < 2; ++kk){
      bf16x8 a[4], b[4];
      int ci = kk * 4 + (lane >> 4);
#pragma unroll
      for (int mi = 0; mi < 4; ++mi){
        int rl = wr * 64 + mi * 16 + (lane & 15);
        a[mi] = *(const bf16x8*)(As + rl * 128 + ((ci ^ (rl & 7)) * 16));
      }
#pragma unroll
      for (int ni = 0; ni < 4; ++ni){
        int sl = wc * 64 + ni * 16 + (lane & 15);
        b[ni] = *(const bf16x8*)(Bs + sl * 128 + ((ci ^ (sl & 7)) * 16));
      }
#pragma unroll
      for (int mi = 0; mi < 4; ++mi)
#pragma unroll
        for (int ni = 0; ni < 4; ++ni)
          acc[mi][ni] = __builtin_amdgcn_mfma_f32_16x16x32_bf16(a[mi], b[ni], acc[mi][ni], 0, 0, 0);
    }
  }
  float bcol[4];
#pragma unroll
  for (int ni = 0; ni < 4; ++ni) bcol[ni] = bias[n0 + wc * 64 + ni * 16 + (lane & 15)];
#pragma unroll
  for (int mi = 0; mi < 4; ++mi)
#pragma unroll
    for (int ni = 0; ni < 4; ++ni)
#pragma unroll
      for (int jj = 0; jj < 4; ++jj){
        int rg = m0 + wr * 64 + mi * 16 + (lane >> 4) * 4 + jj;
        int cg = n0 + wc * 64 + ni * 16 + (lane & 15);
        __builtin_nontemporal_store(f2bf(acc[mi][ni][jj] + bcol[ni]),
                                    &xw[(size_t)rg * 4096 + cg]);
      }
}

// ---------------- K2: persistent recurrent kernel ----------------
// WP (131072B): fragment-major: fragment (kc,g,lane) at ((kc*4+g)*64+lane)*16,
// holding w_h[k=kc*32+q*8..+8][col=g*1024+j0+rr].
// K split into 4 chunks of 8 kc; chunk c depends on producers [c*16, c*16+16).
// WG processes chunks in order (rot+b)&3. Poll lane-group g covers the b=g-th
// processed chunk's 16 producers -> ballot mask 0xFFFF << (16*g).
// Flags: flags[((w<<6)+wg)*4] (16B stride).
#define LDA(k, BASE, OFF) asm volatile("global_load_dwordx4 %0, %1, off offset:" #OFF \
                                 : "=v"(ap[k]) : "v"(BASE) : "memory")   // cacheable
#define LDCHUNK(B, BASE) \
  LDA((B)*8+0, BASE, 0);   LDA((B)*8+1, BASE, 64);  LDA((B)*8+2, BASE, 128); LDA((B)*8+3, BASE, 192); \
  LDA((B)*8+4, BASE, 256); LDA((B)*8+5, BASE, 320); LDA((B)*8+6, BASE, 384); LDA((B)*8+7, BASE, 448)
#define WAITV(N) do { asm volatile("s_waitcnt vmcnt(" #N ")" ::: "memory"); \
                      __builtin_amdgcn_sched_barrier(0); } while(0)
#define GBLKR(B, WPC) \
  _Pragma("unroll") \
  for (int i = 0; i < 8; ++i){ \
    bf16x8 a = as_bf(ap[(B) * 8 + i]); \
    _Pragma("unroll") \
    for (int g = 0; g < 4; ++g){ \
      bf16x8 b = *(const bf16x8*)((WPC) + ((i * 4 + g) << 10) + (lane << 4)); \
      acc[g] = __builtin_amdgcn_mfma_f32_16x16x32_bf16(a, b, acc[g], 0, 0, 0); \
    } \
  }
#define POLLLD(V, P) asm volatile("global_load_dword %0, %1, off sc0 sc1\n\ts_waitcnt vmcnt(0)" \
                                  : "=v"(V) : "v"(P) : "memory")
// wait until the b-th processed chunk's 16 producers post step >= t
#define POLLGRP(B) do { \
    while (true){ \
      int v_; POLLLD(v_, fpoll); \
      unsigned long long m_ = __ballot(v_ >= t); \
      if (((m_ >> (16 * (B))) & 0xFFFFull) == 0xFFFFull) break; \
      __builtin_amdgcn_s_sleep(1); \
    } \
  } while (0)

__launch_bounds__(256, 1)
__global__ void k2_rec(const uint16_t* __restrict__ xw, const uint16_t* __restrict__ wT,
                       uint16_t* __restrict__ hbuf, int* __restrict__ flags,
                       float* __restrict__ outp){
  extern __shared__ char sm[];
  char* WP = sm;                       // 131072

  int tid  = threadIdx.x;
  int lane = tid & 63;
  int w    = tid >> 6;                 // wave id = row block = chain id
  int wg = blockIdx.x;
  int j0 = wg * 16;
  int rot = wg & 3;                    // chunk rotation class

  // pin w_h slice in fragment-major layout
#pragma unroll
  for (int i = 0; i < 32; ++i){
    int L = i * 256 + tid;             // fragment id 0..8191
    int kc = L >> 8;
    int g  = (L >> 6) & 3;
    int l6 = L & 63;
    int q_ = (l6 >> 4) & 3;
    int rr_ = l6 & 15;
    i32x4 v = *(const i32x4*)(wT + (size_t)(g * 1024 + j0 + rr_) * 2048 + kc * 32 + q_ * 8);
    *(i32x4*)(WP + (size_t)L * 16) = v;
  }
  __syncthreads();                     // only barrier in the kernel

  const int r0 = w * 16;
  const int q  = lane >> 4;
  const int rr = lane & 15;

  // poll assignment: lane group g checks producer WG ((rot+g)&3)*16 + (lane&15)
  const int chk = (rot + (lane >> 4)) & 3;
  const int* fpoll = flags + (size_t)((w << 6) + (chk << 4) + (lane & 15)) * FLAGSTRIDE;
  int* fpost = flags + (size_t)((w << 6) + wg) * FLAGSTRIDE;

  // chunk bases (WP side; A side is per-step)
  char* WPc0 = WP + (((rot + 0) & 3) << 15);
  char* WPc1 = WP + (((rot + 1) & 3) << 15);
  char* WPc2 = WP + (((rot + 2) & 3) << 15);
  char* WPc3 = WP + (((rot + 3) & 3) << 15);
  const int aOff0 = ((rot + 0) & 3) << 8;   // elements: chunk * 8kc * 32
  const int aOff1 = ((rot + 1) & 3) << 8;
  const int aOff2 = ((rot + 2) & 3) << 8;
  const int aOff3 = ((rot + 3) & 3) << 8;

  float creg[4] = {0.f, 0.f, 0.f, 0.f};

  // xw 3-buffer rotation
  uint16_t xc[4][4], xn[4][4];
  {
    const uint16_t* xp0 = xw + j0 + rr;
    const uint16_t* xp1 = xw + (size_t)1 * (64 * 4096) + j0 + rr;
#pragma unroll
    for (int g = 0; g < 4; ++g)
#pragma unroll
      for (int p = 0; p < 4; ++p){
        xc[g][p] = xp0[(size_t)(r0 + q * 4 + p) * 4096 + g * 1024];
        xn[g][p] = xp1[(size_t)(r0 + q * 4 + p) * 4096 + g * 1024];
      }
  }

  for (int t = 0; t < TSTEPS; ++t){
    // ---- phase-1 poll: only the FIRST chunk's 16 producers gate the start.
    //      The same ballot tells us (for free) which later chunks are ready.
    bool need1 = false, need2 = false, need3 = false;
    if (t > 0){
      while (true){
        int v; POLLLD(v, fpoll);
        unsigned long long m = __ballot(v >= t);
        if ((m & 0xFFFFull) == 0xFFFFull){
          need1 = ((m >> 16) & 0xFFFFull) != 0xFFFFull;
          need2 = ((m >> 32) & 0xFFFFull) != 0xFFFFull;
          need3 = ((m >> 48) & 0xFFFFull) != 0xFFFFull;
          break;
        }
        __builtin_amdgcn_s_sleep(1);
      }
    }

    const uint16_t* hsrc = hbuf + (size_t)t * (NBATCH * NHID);
    const uint16_t* aB = hsrc + (size_t)(r0 + rr) * 1024 + q * 8;

    i32x4 ap[32];
    f32x4 acc[4];
#pragma unroll
    for (int g = 0; g < 4; ++g) acc[g] = (f32x4){0.f, 0.f, 0.f, 0.f};

    // ---- chunk 0 loads; chunk 1 gated by need1 (free if ready) ----
    LDCHUNK(0, aB + aOff0);
    if (need1) POLLGRP(1);             // rare; embedded vmcnt(0) just drains c0
    LDCHUNK(1, aB + aOff1);
    WAITV(8);  GBLKR(0, WPc0);         // c0 drained; c1 in flight under GEMM

    if (need2) POLLGRP(2);             // rare
    LDCHUNK(2, aB + aOff2);
    WAITV(8);  GBLKR(1, WPc1);         // c1 drained; c2 in flight

    if (need3) POLLGRP(3);             // rare
    LDCHUNK(3, aB + aOff3);
    // xw t+2 nt prefetch (16 loads, youngest)
    uint16_t xn2[4][4];
    {
      int tn = (t < TSTEPS - 2) ? t + 2 : TSTEPS - 1;   // uniform load count
      const uint16_t* xp = xw + (size_t)tn * (64 * 4096) + j0 + rr;
#pragma unroll
      for (int g = 0; g < 4; ++g)
#pragma unroll
        for (int p = 0; p < 4; ++p)
          xn2[g][p] = __builtin_nontemporal_load(
                        &xp[(size_t)(r0 + q * 4 + p) * 4096 + g * 1024]);
    }
    WAITV(24); GBLKR(2, WPc2);         // c2 drained (8 c3 + 16 xw remain)
    WAITV(16); GBLKR(3, WPc3);         // c3 drained (16 xw remain)

    // ---- epilogue: in-register gate math; ONLY 4 bf16 sc1 stores ----
    uint16_t* hdst = hbuf + (size_t)(t + 1) * (NBATCH * NHID);
#pragma unroll
    for (int p = 0; p < 4; ++p){
      float G = acc[0][p] + bf2f(xc[0][p]);
      float I = acc[1][p] + bf2f(xc[1][p]);
      float F = acc[2][p] + bf2f(xc[2][p]);
      float O = acc[3][p] + bf2f(xc[3][p]);
      G = tanhfast(G); I = sigm(I); F = sigm(F); O = sigm(O);
      float c = G * I + creg[p] * F;
      creg[p] = c;
      float h = tanhfast(c) * O;
      __hip_atomic_store(hdst + (size_t)(r0 + q * 4 + p) * 1024 + j0 + rr,
                         f2bf(h), __ATOMIC_RELAXED, AGENT);   // sc1 -> through to L3
    }

    // per-wave drain (4 h-stores + xw loads), then flag post (sc0 sc1)
    asm volatile("s_waitcnt vmcnt(0)" ::: "memory");
    if (lane == 0){
      int tv = t + 1;
      asm volatile("global_store_dword %0, %1, off sc0 sc1"
                   :: "v"(fpost), "v"(tv) : "memory");
    }

    // rotate xw regs (loads already drained)
#pragma unroll
    for (int g = 0; g < 4; ++g)
#pragma unroll
      for (int p = 0; p < 4; ++p){
        xc[g][p] = xn[g][p];
        xn[g][p] = xn2[g][p];
      }
  }
}

// ---------------- K3: hbuf[1..512] bf16 -> outp fp32 (nt stores) ----------------
__global__ void k3_out(const uint16_t* __restrict__ hb, float* __restrict__ outp, int n8){
  int stride = gridDim.x * blockDim.x;
  for (int i = blockIdx.x * blockDim.x + threadIdx.x; i < n8; i += stride){
    i32x4 v = *(const i32x4*)(hb + (size_t)(NBATCH * NHID) + (size_t)i * 8);
    const uint16_t* u = (const uint16_t*)&v;
    fl4 o0, o1;
    o0.x = bf2f(u[0]); o0.y = bf2f(u[1]); o0.z = bf2f(u[2]); o0.w = bf2f(u[3]);
    o1.x = bf2f(u[4]); o1.y = bf2f(u[5]); o1.z = bf2f(u[6]); o1.w = bf2f(u[7]);
    __builtin_nontemporal_store(o0, (fl4*)(outp + (size_t)i * 8));
    __builtin_nontemporal_store(o1, (fl4*)(outp + (size_t)i * 8 + 4));
  }
}

extern "C" void kernel_launch(void* const* d_in, const int* in_sizes, int n_in,
                              void* d_out, int out_size, void* d_ws, size_t ws_size,
                              hipStream_t stream){
  const float* embeds = (const float*)d_in[0];   // [512,64,1024]
  const float* w      = (const float*)d_in[1];   // [2048,4096]
  const float* bias   = (const float*)d_in[2];   // [4096]
  float* outp = (float*)d_out;
  char* ws = (char*)d_ws;

  const size_t o_ebf = 0;                                   // bf16 [32768][1024]
  const size_t o_wT  = o_ebf + (size_t)32768 * 1024 * 2;    // bf16 [4096][2048]
  const size_t o_xw  = o_wT  + (size_t)4096 * 2048 * 2;     // bf16 [32768][4096]
  const size_t o_hb  = o_xw  + (size_t)32768 * 4096 * 2;    // bf16 [513][64][1024]
  const size_t o_fl  = o_hb  + (size_t)513 * 64 * 1024 * 2; // int [256*4] packed

  uint16_t* ebf  = (uint16_t*)(ws + o_ebf);
  uint16_t* wT   = (uint16_t*)(ws + o_wT);
  uint16_t* xw   = (uint16_t*)(ws + o_xw);
  uint16_t* hbuf = (uint16_t*)(ws + o_hb);
  int*      flags= (int*)(ws + o_fl);

  hipMemsetAsync(ws + o_hb, 0, (size_t)64 * 1024 * 2, stream);            // h_0 = 0
  hipMemsetAsync(ws + o_fl, 0, 256 * FLAGSTRIDE * sizeof(int), stream);   // flags = 0 every replay

  k0a_cvt<<<2048, 256, 0, stream>>>(embeds, ebf, (512 * 64 * 1024) / 8);
  k0b_trans<<<dim3(32, 64), 256, 0, stream>>>(w, wT);
  k1_xw<<<8192, 256, 0, stream>>>(ebf, wT, bias, xw);

  (void)hipFuncSetAttribute((const void*)k2_rec,
                            hipFuncAttributeMaxDynamicSharedMemorySize, 131072);
  k2_rec<<<NWG2, 256, 131072, stream>>>(xw, wT, hbuf, flags, outp);

  k3_out<<<2048, 256, 0, stream>>>(hbuf, outp, (512 * 64 * 1024) / 8);
}